// Round 2
// baseline (94.193 us; speedup 1.0000x reference)
//
#include <hip/hip_runtime.h>
#include <stdint.h>

typedef float  f32x4 __attribute__((ext_vector_type(4)));
typedef int    i32x4 __attribute__((ext_vector_type(4)));

// ---------------------------------------------------------------------------
// JAX threefry2x32 block cipher (20 rounds), bit-exact with jax._src.prng.
// ---------------------------------------------------------------------------
static __device__ __forceinline__ uint32_t rotl32(uint32_t x, int r) {
  return (x << r) | (x >> (32 - r));
}

static __device__ __forceinline__ void threefry2x32(uint32_t k0, uint32_t k1,
                                                    uint32_t& x0, uint32_t& x1) {
  const uint32_t ks0 = k0, ks1 = k1, ks2 = k0 ^ k1 ^ 0x1BD11BDAu;
  x0 += ks0; x1 += ks1;
#define TF4(a, b, c, d)                          \
  x0 += x1; x1 = rotl32(x1, (a)); x1 ^= x0;      \
  x0 += x1; x1 = rotl32(x1, (b)); x1 ^= x0;      \
  x0 += x1; x1 = rotl32(x1, (c)); x1 ^= x0;      \
  x0 += x1; x1 = rotl32(x1, (d)); x1 ^= x0;
  TF4(13, 15, 26, 6)   x0 += ks1; x1 += ks2 + 1u;
  TF4(17, 29, 16, 24)  x0 += ks2; x1 += ks0 + 2u;
  TF4(13, 15, 26, 6)   x0 += ks0; x1 += ks1 + 3u;
  TF4(17, 29, 16, 24)  x0 += ks1; x1 += ks2 + 4u;
  TF4(13, 15, 26, 6)   x0 += ks2; x1 += ks0 + 5u;
#undef TF4
}

static __device__ __forceinline__ float bits_to_unit_float(uint32_t bits) {
  // JAX _uniform: bitcast((bits >> 9) | 0x3f800000) - 1.0  -> [0, 1)
  return __uint_as_float((bits >> 9) | 0x3f800000u) - 1.0f;
}

// ---------------------------------------------------------------------------
// Kernel 1: compute idx[T] (jitter gather indices), partitionable-threefry
// semantics (JAX >= 0.4.30 default: jax_threefry_partitionable=True).
//   key(42)            = (0, 42)
//   split:   k_rep     = cipher((0,42), (0,0)) ; k_dir = cipher((0,42), (0,1))
//   bits[t] (32-bit)   = y0 ^ y1 where (y0,y1) = cipher(k, (0, t))
// ---------------------------------------------------------------------------
__global__ void jitter_idx_kernel(int* __restrict__ idx, int T) {
  int t = blockIdx.x * blockDim.x + threadIdx.x;
  if (t >= T) return;

  // split keys (recomputed per thread; 8192 threads total, negligible)
  uint32_t kr0 = 0u, kr1 = 0u; threefry2x32(0u, 42u, kr0, kr1);  // k_rep
  uint32_t kd0 = 0u, kd1 = 1u; threefry2x32(0u, 42u, kd0, kd1);  // k_dir

  uint32_t a0 = 0u, a1 = (uint32_t)t; threefry2x32(kr0, kr1, a0, a1);
  const uint32_t rep_bits = a0 ^ a1;
  uint32_t b0 = 0u, b1 = (uint32_t)t; threefry2x32(kd0, kd1, b0, b1);
  const uint32_t dir_bits = b0 ^ b1;

  const bool replace = bits_to_unit_float(rep_bits) < 0.12f;   // P_JITTER
  int dir = (bits_to_unit_float(dir_bits) < 0.5f) ? 1 : -1;
  if (t == 0)     dir = 1;    // boundary overrides (applied to direction)
  if (t == T - 1) dir = -1;

  idx[t] = replace ? (t + dir) : t;
}

// ---------------------------------------------------------------------------
// Kernel 2: out[row, t] = in[row, idx[t]], row = b*C + c. Pure memory-bound.
// 4 outputs per thread: i32x4 idx load, 4 scalar gathers (addresses are t+-1,
// same cache lines as a coalesced stream), one f32x4 non-temporal store.
// ---------------------------------------------------------------------------
__global__ void __launch_bounds__(256) jitter_gather_kernel(
    const float* __restrict__ in, const int* __restrict__ idx,
    float* __restrict__ out, int T4, int total4) {
  int i = blockIdx.x * blockDim.x + threadIdx.x;
  const int stride = gridDim.x * blockDim.x;
  for (; i < total4; i += stride) {
    const int row = i / T4;            // T4 = 2048 (runtime), magic-div
    const int t  = (i - row * T4) << 2;
    const long long base = (long long)row * ((long long)T4 << 2);
    const float* __restrict__ rin = in + base;

    const i32x4 iv = *reinterpret_cast<const i32x4*>(idx + t);
    f32x4 o;
    o.x = rin[iv.x];
    o.y = rin[iv.y];
    o.z = rin[iv.z];
    o.w = rin[iv.w];
    __builtin_nontemporal_store(o, reinterpret_cast<f32x4*>(out + base + t));
  }
}

extern "C" void kernel_launch(void* const* d_in, const int* in_sizes, int n_in,
                              void* d_out, int out_size, void* d_ws, size_t ws_size,
                              hipStream_t stream) {
  const float* in = (const float*)d_in[0];
  float* out = (float*)d_out;
  int* idx = (int*)d_ws;                 // 8192 * 4 B = 32 KiB scratch

  const int T = 8192;                    // time axis (shape [32, 256, 8192])
  const int rows = in_sizes[0] / T;      // 32 * 256 = 8192
  const int T4 = T / 4;
  const int total4 = rows * T4;          // 16,777,216 float4 outputs

  jitter_idx_kernel<<<(T + 255) / 256, 256, 0, stream>>>(idx, T);
  jitter_gather_kernel<<<2048, 256, 0, stream>>>(in, idx, out, T4, total4);
}